// Round 11
// baseline (539.476 us; speedup 1.0000x reference)
//
#include <hip/hip_runtime.h>

#define NSTEPS 3
#define SN (8192 * 64)

typedef unsigned short u16;
typedef unsigned int   u32;
typedef unsigned long long u64;
typedef __bf16 bf16x8 __attribute__((ext_vector_type(8)));
typedef float  f32x4  __attribute__((ext_vector_type(4)));

typedef __attribute__((address_space(1))) void gvoid_t;
typedef __attribute__((address_space(3))) void lvoid_t;

__device__ __forceinline__ void async_copy16(const void* g, void* l) {
  __builtin_amdgcn_global_load_lds((gvoid_t*)g, (lvoid_t*)l, 16, 0, 0);
}
__device__ __forceinline__ u16 bfc(float x) {
  union { __bf16 b; u16 u; } v; v.b = (__bf16)x; return v.u;
}
__device__ __forceinline__ u64 pack4(float a, float b, float c, float d) {
  return (u64)bfc(a) | ((u64)bfc(b) << 16) | ((u64)bfc(c) << 32) | ((u64)bfc(d) << 48);
}
__device__ __forceinline__ float ftanh(float x) {
  float e = __expf(2.f * x);
  return 1.f - 2.f / (e + 1.f);
}

// ---------------- prep kernels ----------------

// base1[j] = b1[j] + sum_c ctx[c] * W1[(65+c)*1024 + j]
__global__ __launch_bounds__(256) void k_base1(
    const float* __restrict__ W1, const float* __restrict__ b1,
    const float* __restrict__ ctx, float* __restrict__ base1) {
  int j = blockIdx.x * 256 + threadIdx.x;
  float s = b1[j];
  for (int c = 0; c < 256; ++c)
    s += ctx[c] * W1[(size_t)(65 + c) * 1024 + j];
  base1[j] = s;
}

// Pack W[K][N] f32 -> fragment-linear bf16: fid = nt*KS + ks, lane holds
// W[ks*32+(lane>>4)*8+j][nt*16+(lane&15)], j=0..7.  frag = 1024B.
__global__ __launch_bounds__(256) void k_pack(
    const float* __restrict__ W, u16* __restrict__ P, int ksl, int N) {
  int gid = blockIdx.x * 256 + threadIdx.x;
  int lane = gid & 63, fid = gid >> 6;
  int ks = fid & ((1 << ksl) - 1);
  int nt = fid >> ksl;
  int n  = nt * 16 + (lane & 15);
  int k0 = ks * 32 + (lane >> 4) * 8;
  u64 lo = pack4(W[(size_t)k0 * N + n], W[(size_t)(k0 + 1) * N + n],
                 W[(size_t)(k0 + 2) * N + n], W[(size_t)(k0 + 3) * N + n]);
  u64 hi = pack4(W[(size_t)(k0 + 4) * N + n], W[(size_t)(k0 + 5) * N + n],
                 W[(size_t)(k0 + 6) * N + n], W[(size_t)(k0 + 7) * N + n]);
  u64* dst = (u64*)(P + (size_t)gid * 8);
  dst[0] = lo; dst[1] = hi;
}

// ---------------- k_l1: RK-update + layer1 (h1 computed ONCE) ----------------
__global__ __launch_bounds__(512, 4) void k_l1(
    const float* __restrict__ theta0, float* __restrict__ th,
    float* __restrict__ acb, const float* __restrict__ kpart,
    const float* __restrict__ b3, const float* __restrict__ base1,
    const float* __restrict__ w1t, const u16* __restrict__ P1,
    u16* __restrict__ h1, float t_s, float a_h, float wgp, int mode) {
  __shared__ u16 xs[32 * 64];          // 4 KB, 128B rows, slot ^= row&7
  __shared__ float bias[1024];         // 4 KB
  __shared__ u16 bounce[8][32 * 16];   // 8 KB, 1 KB per wave
  const int tid = threadIdx.x, wid = tid >> 6, lane = tid & 63;
  const int lrow = lane & 15, lk4 = lane >> 4;
  const int brow = blockIdx.x * 32;

  bias[tid]       = base1[tid]       + t_s * w1t[tid];
  bias[tid + 512] = base1[tid + 512] + t_s * w1t[tid + 512];

  {
    int row = tid >> 4, d = (tid & 15) * 4;
    int gi = (brow + row) * 64 + d;
    f32x4 x;
    if (mode == 0) {
      x = *(const f32x4*)(theta0 + gi);
    } else {
      f32x4 kv = *(const f32x4*)(kpart + gi);
      f32x4 k1 = *(const f32x4*)(kpart + SN + gi);
      f32x4 k2 = *(const f32x4*)(kpart + 2 * SN + gi);
      f32x4 k3 = *(const f32x4*)(kpart + 3 * SN + gi);
      f32x4 bv = *(const f32x4*)(b3 + d);
      f32x4 t  = *(f32x4*)(th + gi);
      f32x4 a  = *(f32x4*)(acb + gi);
#pragma unroll
      for (int j = 0; j < 4; ++j) kv[j] += k1[j] + k2[j] + k3[j] + bv[j];
      if (mode == 1) {
#pragma unroll
        for (int j = 0; j < 4; ++j) { a[j] += wgp * kv[j]; x[j] = t[j] + a_h * kv[j]; }
        *(f32x4*)(acb + gi) = a;
      } else {
#pragma unroll
        for (int j = 0; j < 4; ++j) t[j] += a[j] + wgp * kv[j];
        *(f32x4*)(th + gi) = t;
        f32x4 z = {0.f, 0.f, 0.f, 0.f};
        *(f32x4*)(acb + gi) = z;
        x = t;
      }
    }
    int slot = d >> 3, half = (d >> 2) & 1;
    *(u64*)((char*)xs + row * 128 + ((slot ^ (row & 7)) << 4) + half * 8)
        = pack4(x[0], x[1], x[2], x[3]);
  }
  __syncthreads();

  u16* bnc = &bounce[wid][0];
#pragma unroll 1
  for (int nt = 0; nt < 8; ++nt) {
    const int n0 = wid * 128 + nt * 16;
    f32x4 acc[2] = {{0.f,0.f,0.f,0.f},{0.f,0.f,0.f,0.f}};
#pragma unroll
    for (int ks = 0; ks < 2; ++ks) {
      bf16x8 pw = *(const bf16x8*)(P1 + ((size_t)((n0 >> 4) * 2 + ks) << 9) + lane * 8);
#pragma unroll
      for (int st = 0; st < 2; ++st) {
        int row = st * 16 + lrow;
        bf16x8 xa = *(const bf16x8*)((char*)xs + row * 128 +
                                     (((ks * 4 + lk4) ^ (row & 7)) << 4));
        acc[st] = __builtin_amdgcn_mfma_f32_16x16x32_bf16(pw, xa, acc[st], 0, 0, 0);
      }
    }
    float bb0 = bias[n0 + lk4 * 4], bb1 = bias[n0 + lk4 * 4 + 1];
    float bb2 = bias[n0 + lk4 * 4 + 2], bb3 = bias[n0 + lk4 * 4 + 3];
#pragma unroll
    for (int st = 0; st < 2; ++st) {
      u64 pk = pack4(ftanh(acc[st][0] + bb0), ftanh(acc[st][1] + bb1),
                     ftanh(acc[st][2] + bb2), ftanh(acc[st][3] + bb3));
      *(u64*)((char*)bnc + (st * 16 + lrow) * 32 + lk4 * 8) = pk;
    }
    asm volatile("s_waitcnt lgkmcnt(0)" ::: "memory");
    bf16x8 ld = *(const bf16x8*)((char*)bnc + lane * 16);
    *(bf16x8*)(h1 + (size_t)(brow + (lane >> 1)) * 1024 + n0 + (lane & 1) * 8) = ld;
  }
}

// ---------------- k_fwd: layer2 + tanh + layer3-partial ----------------
// Tile 32 samples x 256 h2 cols (grid 256 x 4), 256 thr = 4 waves, BK=64.
// A (h1): LDS dbuf (4 KB/buf, 128B rows, slot^=(row&7)), 2-deep prefetch,
// counted-vmcnt (FIFO retire: A(t) done <=> outstanding <= #newer ops).
// B (W2): register ping-pong from fragment-linear P2 (L2-hot).
// 25.6 KB LDS + <=128 VGPR -> 4 blocks/CU = 4 waves/SIMD (2x round 10).
__global__ __launch_bounds__(256, 4) void k_fwd(
    const u16* __restrict__ h1, const u16* __restrict__ P2,
    const float* __restrict__ b2, const u16* __restrict__ P3,
    float* __restrict__ kpart) {
  __shared__ u16 Ab[2][32 * 64];     // 2 x 4 KB
  __shared__ u16 h2L[32 * 256];      // 16 KB
  __shared__ float b2l[256];         // 1 KB
  const int tid = threadIdx.x, wid = tid >> 6, lane = tid & 63;
  const int lrow = lane & 15, lk4 = lane >> 4;
  const int brow = blockIdx.x * 32, bcol = blockIdx.y * 256;
  const int wn = wid;                 // wave col-block (4 x 64 cols)

  b2l[tid] = b2[bcol + tid];

  // A stage: 32 rows x 64 k x 2B = 4KB; dest linear tid*16; source k-slot
  // pre-swizzled s8u = (tid&7) ^ (row&7).
  auto stageA = [&](int buf, int k0) {
    int pr = tid >> 3, s8u = (tid & 7) ^ (pr & 7);
    async_copy16((const char*)h1 + ((size_t)(brow + pr) * 1024 + k0 + s8u * 8) * 2,
                 (char*)&Ab[buf][0] + tid * 16);
  };

  bf16x8 Bf[2][4];     // even k-slices in Bf[0], odd in Bf[1]
  auto loadB = [&](int pb, int ks) {
#pragma unroll
    for (int n = 0; n < 4; ++n)
      Bf[pb][n] = *(const bf16x8*)(P2 +
          ((size_t)(((bcol >> 4) + wn * 4 + n) * 32 + ks) << 9) + lane * 8);
  };

  // prologue: A 2-deep, B slice 0
  stageA(0, 0);
  asm volatile("" ::: "memory");
  stageA(1, 64);
  asm volatile("" ::: "memory");
  loadB(0, 0);

  f32x4 acc[4][2] = {};
  int cur = 0;
#pragma unroll 1
  for (int t = 0; t < 16; ++t) {
    // retire A(t): N = ops issued after it (prologue/steady/tail cases)
    if (t == 0)       asm volatile("s_waitcnt vmcnt(5)"  ::: "memory");
    else if (t == 1)  asm volatile("s_waitcnt vmcnt(13)" ::: "memory");
    else if (t == 15) asm volatile("s_waitcnt vmcnt(16)" ::: "memory");
    else              asm volatile("s_waitcnt vmcnt(17)" ::: "memory");
    __builtin_amdgcn_s_barrier();      // all waves' A(t) landed

    bf16x8 af0[2], af1[2];
#pragma unroll
    for (int m = 0; m < 2; ++m) {
      int ar = m * 16 + lrow;
      const char* Arow = (const char*)&Ab[cur][0] + ar * 128;
      af0[m] = *(const bf16x8*)(Arow + ((lk4 ^ (ar & 7)) << 4));
      af1[m] = *(const bf16x8*)(Arow + (((4 + lk4) ^ (ar & 7)) << 4));
    }
    asm volatile("s_waitcnt lgkmcnt(0)" ::: "memory");
    __builtin_amdgcn_s_barrier();      // all waves done reading Ab[cur]
    asm volatile("" ::: "memory");

    if (t < 14) stageA(cur, (t + 2) * 64);   // A first in this iter's FIFO
    asm volatile("" ::: "memory");
    loadB(1, 2 * t + 1);

#pragma unroll
    for (int n = 0; n < 4; ++n)
#pragma unroll
      for (int m = 0; m < 2; ++m)
        acc[n][m] = __builtin_amdgcn_mfma_f32_16x16x32_bf16(Bf[0][n], af0[m],
                                                            acc[n][m], 0, 0, 0);
    if (t < 15) loadB(0, 2 * t + 2);
#pragma unroll
    for (int n = 0; n < 4; ++n)
#pragma unroll
      for (int m = 0; m < 2; ++m)
        acc[n][m] = __builtin_amdgcn_mfma_f32_16x16x32_bf16(Bf[1][n], af1[m],
                                                            acc[n][m], 0, 0, 0);
    cur ^= 1;
  }

  // h2 tile: tanh -> h2L[32][256] (512B rows), swizzled 16B slots
#pragma unroll
  for (int n = 0; n < 4; ++n) {
    int cb = wn * 64 + n * 16 + lk4 * 4;     // 4 consecutive cols
    float c0 = b2l[cb], c1 = b2l[cb + 1], c2 = b2l[cb + 2], c3 = b2l[cb + 3];
    int o = cb >> 3, half = (cb >> 2) & 1;
#pragma unroll
    for (int m = 0; m < 2; ++m) {
      int smp = m * 16 + lrow;
      u64 pk = pack4(ftanh(acc[n][m][0] + c0), ftanh(acc[n][m][1] + c1),
                     ftanh(acc[n][m][2] + c2), ftanh(acc[n][m][3] + c3));
      int sl = (o & 24) | ((o & 7) ^ (smp & 7));
      *(u64*)((char*)h2L + smp * 512 + (sl << 4) + half * 8) = pk;
    }
  }
  __syncthreads();

  // L3 partial: D[kcol][sample]; wave = 32 kcols x 16 samples, K=256
  {
    const int st = wid >> 1, ktp = wid & 1;
    const int smp = st * 16 + lrow;
    const char* Ar = (const char*)h2L + smp * 512;
    const int sx = smp & 7;
    f32x4 a3[2] = {};
#pragma unroll
    for (int ks = 0; ks < 8; ++ks) {
      int slu = ks * 4 + lk4;
      bf16x8 hf = *(const bf16x8*)(Ar + (((slu & 24) | ((slu & 7) ^ sx)) << 4));
#pragma unroll
      for (int n = 0; n < 2; ++n) {
        int fid = (ktp * 2 + n) * 32 + blockIdx.y * 8 + ks;
        bf16x8 pw = *(const bf16x8*)(P3 + ((size_t)fid << 9) + lane * 8);
        a3[n] = __builtin_amdgcn_mfma_f32_16x16x32_bf16(pw, hf, a3[n], 0, 0, 0);
      }
    }
    float* kp = kpart + (size_t)blockIdx.y * SN;
#pragma unroll
    for (int n = 0; n < 2; ++n)
      *(f32x4*)(kp + (size_t)(brow + smp) * 64 + (ktp * 2 + n) * 16 + lk4 * 4) = a3[n];
  }
}

// ---------------- final output ----------------
__global__ __launch_bounds__(256) void k_out(
    const float* __restrict__ th, const float* __restrict__ acb,
    const float* __restrict__ kpart, const float* __restrict__ b3,
    float* __restrict__ out, float w) {
  int gi = (blockIdx.x * 256 + threadIdx.x) * 4;
  f32x4 kv = *(const f32x4*)(kpart + gi);
  f32x4 k1 = *(const f32x4*)(kpart + SN + gi);
  f32x4 k2 = *(const f32x4*)(kpart + 2 * SN + gi);
  f32x4 k3 = *(const f32x4*)(kpart + 3 * SN + gi);
  f32x4 bv = *(const f32x4*)(b3 + (gi & 63));
  f32x4 t  = *(const f32x4*)(th + gi);
  f32x4 a  = *(const f32x4*)(acb + gi);
#pragma unroll
  for (int j = 0; j < 4; ++j)
    t[j] += a[j] + w * (kv[j] + k1[j] + k2[j] + k3[j] + bv[j]);
  *(f32x4*)(out + gi) = t;
}

// ---------------- host ----------------

extern "C" void kernel_launch(void* const* d_in, const int* in_sizes, int n_in,
                              void* d_out, int out_size, void* d_ws, size_t ws_size,
                              hipStream_t stream) {
  const float* theta0 = (const float*)d_in[0];
  const float* ctx    = (const float*)d_in[1];
  const float* W1     = (const float*)d_in[2];
  const float* b1     = (const float*)d_in[3];
  const float* W2     = (const float*)d_in[4];
  const float* b2     = (const float*)d_in[5];
  const float* W3     = (const float*)d_in[6];
  const float* b3     = (const float*)d_in[7];
  const float* w1t    = W1 + (size_t)64 * 1024;   // time row of W1

  char* ws = (char*)d_ws;
  size_t o = 0;
  float* th    = (float*)(ws + o); o += (size_t)SN * 4;            // 2 MB
  float* acb   = (float*)(ws + o); o += (size_t)SN * 4;            // 2 MB
  float* base1 = (float*)(ws + o); o += 4096;
  u16* P2  = (u16*)(ws + o); o += (size_t)1024 * 1024 * 2;         // 2 MB
  u16* P1  = (u16*)(ws + o); o += (size_t)64 * 1024 * 2;           // 128 KB
  u16* P3  = (u16*)(ws + o); o += (size_t)1024 * 64 * 2;           // 128 KB
  float* kpart = (float*)(ws + o); o += (size_t)4 * SN * 4;        // 8 MB
  u16* h1  = (u16*)(ws + o); o += (size_t)8192 * 1024 * 2;         // 16 MB

  hipMemcpyAsync(th, theta0, (size_t)SN * 4, hipMemcpyDeviceToDevice, stream);
  hipMemsetAsync(acb, 0, (size_t)SN * 4, stream);

  k_base1<<<dim3(4), 256, 0, stream>>>(W1, b1, ctx, base1);
  k_pack<<<dim3(512), 256, 0, stream>>>(W2, P2, 5, 1024);  // 64 nt x 32 ks
  k_pack<<<dim3(32),  256, 0, stream>>>(W1, P1, 1, 1024);  // 64 nt x 2 ks
  k_pack<<<dim3(32),  256, 0, stream>>>(W3, P3, 5, 64);    // 4 nt x 32 ks

  const float hs = 1.f / NSTEPS;
  const float ah[4] = {0.f, 0.5f * hs, 0.5f * hs, hs};
  const float ct[4] = {0.f, 0.5f, 0.5f, 1.f};

  for (int step = 0; step < NSTEPS; ++step) {
    for (int s = 0; s < 4; ++s) {
      int mode = (step == 0 && s == 0) ? 0 : (s == 0 ? 2 : 1);
      float wgp = (s == 0 || s == 1) ? hs / 6.f : hs / 3.f;
      float t_s = ((float)step + ct[s]) * hs;
      k_l1<<<dim3(256), 512, 0, stream>>>(theta0, th, acb, kpart, b3, base1,
                                          w1t, P1, h1, t_s, ah[s], wgp, mode);
      k_fwd<<<dim3(256, 4), 256, 0, stream>>>(h1, P2, b2, P3, kpart);
    }
  }
  k_out<<<dim3(512), 256, 0, stream>>>(th, acb, kpart, b3, (float*)d_out, hs / 6.f);
}

// Round 12
// 492.784 us; speedup vs baseline: 1.0948x; 1.0948x over previous
//
#include <hip/hip_runtime.h>

#define NSTEPS 2
#define SN (8192 * 64)

typedef unsigned short u16;
typedef unsigned int   u32;
typedef unsigned long long u64;
typedef __bf16 bf16x8 __attribute__((ext_vector_type(8)));
typedef float  f32x4  __attribute__((ext_vector_type(4)));

typedef __attribute__((address_space(1))) void gvoid_t;
typedef __attribute__((address_space(3))) void lvoid_t;

__device__ __forceinline__ void async_copy16(const void* g, void* l) {
  __builtin_amdgcn_global_load_lds((gvoid_t*)g, (lvoid_t*)l, 16, 0, 0);
}
__device__ __forceinline__ u16 bfc(float x) {
  union { __bf16 b; u16 u; } v; v.b = (__bf16)x; return v.u;
}
__device__ __forceinline__ u64 pack4(float a, float b, float c, float d) {
  return (u64)bfc(a) | ((u64)bfc(b) << 16) | ((u64)bfc(c) << 32) | ((u64)bfc(d) << 48);
}
__device__ __forceinline__ float ftanh(float x) {
  float e = __expf(2.f * x);
  return 1.f - 2.f / (e + 1.f);
}

// ---------------- prep kernels ----------------

// base1[j] = b1[j] + sum_c ctx[c] * W1[(65+c)*1024 + j]
__global__ __launch_bounds__(256) void k_base1(
    const float* __restrict__ W1, const float* __restrict__ b1,
    const float* __restrict__ ctx, float* __restrict__ base1) {
  int j = blockIdx.x * 256 + threadIdx.x;
  float s = b1[j];
  for (int c = 0; c < 256; ++c)
    s += ctx[c] * W1[(size_t)(65 + c) * 1024 + j];
  base1[j] = s;
}

// Pack W[K][N] f32 -> fragment-linear bf16: fid = nt*KS + ks, lane holds
// W[ks*32+(lane>>4)*8+j][nt*16+(lane&15)], j=0..7.  frag = 1024B.
__global__ __launch_bounds__(256) void k_pack(
    const float* __restrict__ W, u16* __restrict__ P, int ksl, int N) {
  int gid = blockIdx.x * 256 + threadIdx.x;
  int lane = gid & 63, fid = gid >> 6;
  int ks = fid & ((1 << ksl) - 1);
  int nt = fid >> ksl;
  int n  = nt * 16 + (lane & 15);
  int k0 = ks * 32 + (lane >> 4) * 8;
  u64 lo = pack4(W[(size_t)k0 * N + n], W[(size_t)(k0 + 1) * N + n],
                 W[(size_t)(k0 + 2) * N + n], W[(size_t)(k0 + 3) * N + n]);
  u64 hi = pack4(W[(size_t)(k0 + 4) * N + n], W[(size_t)(k0 + 5) * N + n],
                 W[(size_t)(k0 + 6) * N + n], W[(size_t)(k0 + 7) * N + n]);
  u64* dst = (u64*)(P + (size_t)gid * 8);
  dst[0] = lo; dst[1] = hi;
}

// ---------------- k_l1: RK-update + layer1 (h1 computed ONCE) ----------------
__global__ __launch_bounds__(512, 4) void k_l1(
    const float* __restrict__ theta0, float* __restrict__ th,
    float* __restrict__ acb, const float* __restrict__ kpart,
    const float* __restrict__ b3, const float* __restrict__ base1,
    const float* __restrict__ w1t, const u16* __restrict__ P1,
    u16* __restrict__ h1, float t_s, float a_h, float wgp, int mode) {
  __shared__ u16 xs[32 * 64];          // 4 KB, 128B rows, slot ^= row&7
  __shared__ float bias[1024];         // 4 KB
  __shared__ u16 bounce[8][32 * 16];   // 8 KB, 1 KB per wave
  const int tid = threadIdx.x, wid = tid >> 6, lane = tid & 63;
  const int lrow = lane & 15, lk4 = lane >> 4;
  const int brow = blockIdx.x * 32;

  bias[tid]       = base1[tid]       + t_s * w1t[tid];
  bias[tid + 512] = base1[tid + 512] + t_s * w1t[tid + 512];

  {
    int row = tid >> 4, d = (tid & 15) * 4;
    int gi = (brow + row) * 64 + d;
    f32x4 x;
    if (mode == 0) {
      x = *(const f32x4*)(theta0 + gi);
    } else {
      f32x4 kv = *(const f32x4*)(kpart + gi);
      f32x4 k1 = *(const f32x4*)(kpart + SN + gi);
      f32x4 k2 = *(const f32x4*)(kpart + 2 * SN + gi);
      f32x4 k3 = *(const f32x4*)(kpart + 3 * SN + gi);
      f32x4 bv = *(const f32x4*)(b3 + d);
      f32x4 t  = *(f32x4*)(th + gi);
      f32x4 a  = *(f32x4*)(acb + gi);
#pragma unroll
      for (int j = 0; j < 4; ++j) kv[j] += k1[j] + k2[j] + k3[j] + bv[j];
      if (mode == 1) {
#pragma unroll
        for (int j = 0; j < 4; ++j) { a[j] += wgp * kv[j]; x[j] = t[j] + a_h * kv[j]; }
        *(f32x4*)(acb + gi) = a;
      } else {
#pragma unroll
        for (int j = 0; j < 4; ++j) t[j] += a[j] + wgp * kv[j];
        *(f32x4*)(th + gi) = t;
        f32x4 z = {0.f, 0.f, 0.f, 0.f};
        *(f32x4*)(acb + gi) = z;
        x = t;
      }
    }
    int slot = d >> 3, half = (d >> 2) & 1;
    *(u64*)((char*)xs + row * 128 + ((slot ^ (row & 7)) << 4) + half * 8)
        = pack4(x[0], x[1], x[2], x[3]);
  }
  __syncthreads();

  u16* bnc = &bounce[wid][0];
#pragma unroll 1
  for (int nt = 0; nt < 8; ++nt) {
    const int n0 = wid * 128 + nt * 16;
    f32x4 acc[2] = {{0.f,0.f,0.f,0.f},{0.f,0.f,0.f,0.f}};
#pragma unroll
    for (int ks = 0; ks < 2; ++ks) {
      bf16x8 pw = *(const bf16x8*)(P1 + ((size_t)((n0 >> 4) * 2 + ks) << 9) + lane * 8);
#pragma unroll
      for (int st = 0; st < 2; ++st) {
        int row = st * 16 + lrow;
        bf16x8 xa = *(const bf16x8*)((char*)xs + row * 128 +
                                     (((ks * 4 + lk4) ^ (row & 7)) << 4));
        acc[st] = __builtin_amdgcn_mfma_f32_16x16x32_bf16(pw, xa, acc[st], 0, 0, 0);
      }
    }
    float bb0 = bias[n0 + lk4 * 4], bb1 = bias[n0 + lk4 * 4 + 1];
    float bb2 = bias[n0 + lk4 * 4 + 2], bb3 = bias[n0 + lk4 * 4 + 3];
#pragma unroll
    for (int st = 0; st < 2; ++st) {
      u64 pk = pack4(ftanh(acc[st][0] + bb0), ftanh(acc[st][1] + bb1),
                     ftanh(acc[st][2] + bb2), ftanh(acc[st][3] + bb3));
      *(u64*)((char*)bnc + (st * 16 + lrow) * 32 + lk4 * 8) = pk;
    }
    asm volatile("s_waitcnt lgkmcnt(0)" ::: "memory");
    bf16x8 ld = *(const bf16x8*)((char*)bnc + lane * 16);
    *(bf16x8*)(h1 + (size_t)(brow + (lane >> 1)) * 1024 + n0 + (lane & 1) * 8) = ld;
  }
}

// ---------------- k_fwd: layer2 + tanh + layer3-partial ----------------
// Tile 32 samples x 256 h2 cols (grid 256 x 4), 256 thr = 4 waves, BK=64.
// A (h1): LDS dbuf, 2-deep counted-vmcnt prefetch.
// B (W2): register-streamed from fragment-linear P2, prefetched a FULL
// ITERATION ahead (Bf[2][2][4], static-indexed via unroll-2) so the
// B-consume wait never exposes L2/L3 latency.
// vmcnt FIFO: per iter 9 vmem ops (1 stageA + 8 loadB); A(t) retire counts
// 9 (t=0) / 17 (steady) / 16 (t=15).
__global__ __launch_bounds__(256, 3) void k_fwd(
    const u16* __restrict__ h1, const u16* __restrict__ P2,
    const float* __restrict__ b2, const u16* __restrict__ P3,
    float* __restrict__ kpart) {
  __shared__ u16 Ab[2][32 * 64];     // 2 x 4 KB
  __shared__ u16 h2L[32 * 256];      // 16 KB
  __shared__ float b2l[256];         // 1 KB
  const int tid = threadIdx.x, wid = tid >> 6, lane = tid & 63;
  const int lrow = lane & 15, lk4 = lane >> 4;
  const int brow = blockIdx.x * 32, bcol = blockIdx.y * 256;
  const int wn = wid;                 // wave col-block (4 x 64 cols)

  b2l[tid] = b2[bcol + tid];

  auto stageA = [&](int buf, int k0) {
    int pr = tid >> 3, s8u = (tid & 7) ^ (pr & 7);
    async_copy16((const char*)h1 + ((size_t)(brow + pr) * 1024 + k0 + s8u * 8) * 2,
                 (char*)&Ab[buf][0] + tid * 16);
  };

  bf16x8 Bf[2][2][4];    // [iter-phase][k-slice][n-frag]
  auto loadB = [&](int ph, int sl, int ks) {
#pragma unroll
    for (int n = 0; n < 4; ++n)
      Bf[ph][sl][n] = *(const bf16x8*)(P2 +
          ((size_t)(((bcol >> 4) + wn * 4 + n) * 32 + ks) << 9) + lane * 8);
  };

  // prologue: A 2-deep; B both slices for iter 0
  stageA(0, 0);
  asm volatile("" ::: "memory");
  stageA(1, 64);
  asm volatile("" ::: "memory");
  loadB(0, 0, 0); loadB(0, 1, 1);

  f32x4 acc[4][2] = {};
  int cur = 0;
#pragma unroll 2
  for (int t = 0; t < 16; ++t) {
    // retire A(t): N = vmem ops issued after it
    if (t == 0)       asm volatile("s_waitcnt vmcnt(9)"  ::: "memory");
    else if (t == 15) asm volatile("s_waitcnt vmcnt(16)" ::: "memory");
    else              asm volatile("s_waitcnt vmcnt(17)" ::: "memory");
    __builtin_amdgcn_s_barrier();      // all waves' A(t) landed

    bf16x8 af0[2], af1[2];
#pragma unroll
    for (int m = 0; m < 2; ++m) {
      int ar = m * 16 + lrow;
      const char* Arow = (const char*)&Ab[cur][0] + ar * 128;
      af0[m] = *(const bf16x8*)(Arow + ((lk4 ^ (ar & 7)) << 4));
      af1[m] = *(const bf16x8*)(Arow + (((4 + lk4) ^ (ar & 7)) << 4));
    }
    asm volatile("s_waitcnt lgkmcnt(0)" ::: "memory");
    __builtin_amdgcn_s_barrier();      // all waves done reading Ab[cur]
    asm volatile("" ::: "memory");

    if (t < 14) stageA(cur, (t + 2) * 64);   // A first in this iter's FIFO
    asm volatile("" ::: "memory");
    if (t < 15) {                             // B for iter t+1 (full cover)
      loadB((t + 1) & 1, 0, 2 * t + 2);
      loadB((t + 1) & 1, 1, 2 * t + 3);
    }

#pragma unroll
    for (int n = 0; n < 4; ++n)
#pragma unroll
      for (int m = 0; m < 2; ++m)
        acc[n][m] = __builtin_amdgcn_mfma_f32_16x16x32_bf16(Bf[t & 1][0][n], af0[m],
                                                            acc[n][m], 0, 0, 0);
#pragma unroll
    for (int n = 0; n < 4; ++n)
#pragma unroll
      for (int m = 0; m < 2; ++m)
        acc[n][m] = __builtin_amdgcn_mfma_f32_16x16x32_bf16(Bf[t & 1][1][n], af1[m],
                                                            acc[n][m], 0, 0, 0);
    cur ^= 1;
  }

  // h2 tile: tanh -> h2L[32][256] (512B rows), swizzled 16B slots
#pragma unroll
  for (int n = 0; n < 4; ++n) {
    int cb = wn * 64 + n * 16 + lk4 * 4;     // 4 consecutive cols
    float c0 = b2l[cb], c1 = b2l[cb + 1], c2 = b2l[cb + 2], c3 = b2l[cb + 3];
    int o = cb >> 3, half = (cb >> 2) & 1;
#pragma unroll
    for (int m = 0; m < 2; ++m) {
      int smp = m * 16 + lrow;
      u64 pk = pack4(ftanh(acc[n][m][0] + c0), ftanh(acc[n][m][1] + c1),
                     ftanh(acc[n][m][2] + c2), ftanh(acc[n][m][3] + c3));
      int sl = (o & 24) | ((o & 7) ^ (smp & 7));
      *(u64*)((char*)h2L + smp * 512 + (sl << 4) + half * 8) = pk;
    }
  }
  __syncthreads();

  // L3 partial: D[kcol][sample]; wave = 32 kcols x 16 samples, K=256
  {
    const int st = wid >> 1, ktp = wid & 1;
    const int smp = st * 16 + lrow;
    const char* Ar = (const char*)h2L + smp * 512;
    const int sx = smp & 7;
    f32x4 a3[2] = {};
#pragma unroll
    for (int ks = 0; ks < 8; ++ks) {
      int slu = ks * 4 + lk4;
      bf16x8 hf = *(const bf16x8*)(Ar + (((slu & 24) | ((slu & 7) ^ sx)) << 4));
#pragma unroll
      for (int n = 0; n < 2; ++n) {
        int fid = (ktp * 2 + n) * 32 + blockIdx.y * 8 + ks;
        bf16x8 pw = *(const bf16x8*)(P3 + ((size_t)fid << 9) + lane * 8);
        a3[n] = __builtin_amdgcn_mfma_f32_16x16x32_bf16(pw, hf, a3[n], 0, 0, 0);
      }
    }
    float* kp = kpart + (size_t)blockIdx.y * SN;
#pragma unroll
    for (int n = 0; n < 2; ++n)
      *(f32x4*)(kp + (size_t)(brow + smp) * 64 + (ktp * 2 + n) * 16 + lk4 * 4) = a3[n];
  }
}

// ---------------- final output ----------------
__global__ __launch_bounds__(256) void k_out(
    const float* __restrict__ th, const float* __restrict__ acb,
    const float* __restrict__ kpart, const float* __restrict__ b3,
    float* __restrict__ out, float w) {
  int gi = (blockIdx.x * 256 + threadIdx.x) * 4;
  f32x4 kv = *(const f32x4*)(kpart + gi);
  f32x4 k1 = *(const f32x4*)(kpart + SN + gi);
  f32x4 k2 = *(const f32x4*)(kpart + 2 * SN + gi);
  f32x4 k3 = *(const f32x4*)(kpart + 3 * SN + gi);
  f32x4 bv = *(const f32x4*)(b3 + (gi & 63));
  f32x4 t  = *(const f32x4*)(th + gi);
  f32x4 a  = *(const f32x4*)(acb + gi);
#pragma unroll
  for (int j = 0; j < 4; ++j)
    t[j] += a[j] + w * (kv[j] + k1[j] + k2[j] + k3[j] + bv[j]);
  *(f32x4*)(out + gi) = t;
}

// ---------------- host ----------------

extern "C" void kernel_launch(void* const* d_in, const int* in_sizes, int n_in,
                              void* d_out, int out_size, void* d_ws, size_t ws_size,
                              hipStream_t stream) {
  const float* theta0 = (const float*)d_in[0];
  const float* ctx    = (const float*)d_in[1];
  const float* W1     = (const float*)d_in[2];
  const float* b1     = (const float*)d_in[3];
  const float* W2     = (const float*)d_in[4];
  const float* b2     = (const float*)d_in[5];
  const float* W3     = (const float*)d_in[6];
  const float* b3     = (const float*)d_in[7];
  const float* w1t    = W1 + (size_t)64 * 1024;   // time row of W1

  char* ws = (char*)d_ws;
  size_t o = 0;
  float* th    = (float*)(ws + o); o += (size_t)SN * 4;            // 2 MB
  float* acb   = (float*)(ws + o); o += (size_t)SN * 4;            // 2 MB
  float* base1 = (float*)(ws + o); o += 4096;
  u16* P2  = (u16*)(ws + o); o += (size_t)1024 * 1024 * 2;         // 2 MB
  u16* P1  = (u16*)(ws + o); o += (size_t)64 * 1024 * 2;           // 128 KB
  u16* P3  = (u16*)(ws + o); o += (size_t)1024 * 64 * 2;           // 128 KB
  float* kpart = (float*)(ws + o); o += (size_t)4 * SN * 4;        // 8 MB
  u16* h1  = (u16*)(ws + o); o += (size_t)8192 * 1024 * 2;         // 16 MB

  hipMemcpyAsync(th, theta0, (size_t)SN * 4, hipMemcpyDeviceToDevice, stream);
  hipMemsetAsync(acb, 0, (size_t)SN * 4, stream);

  k_base1<<<dim3(4), 256, 0, stream>>>(W1, b1, ctx, base1);
  k_pack<<<dim3(512), 256, 0, stream>>>(W2, P2, 5, 1024);  // 64 nt x 32 ks
  k_pack<<<dim3(32),  256, 0, stream>>>(W1, P1, 1, 1024);  // 64 nt x 2 ks
  k_pack<<<dim3(32),  256, 0, stream>>>(W3, P3, 5, 64);    // 4 nt x 32 ks

  const float hs = 1.f / NSTEPS;
  const float ah[4] = {0.f, 0.5f * hs, 0.5f * hs, hs};
  const float ct[4] = {0.f, 0.5f, 0.5f, 1.f};

  for (int step = 0; step < NSTEPS; ++step) {
    for (int s = 0; s < 4; ++s) {
      int mode = (step == 0 && s == 0) ? 0 : (s == 0 ? 2 : 1);
      float wgp = (s == 0 || s == 1) ? hs / 6.f : hs / 3.f;
      float t_s = ((float)step + ct[s]) * hs;
      k_l1<<<dim3(256), 512, 0, stream>>>(theta0, th, acb, kpart, b3, base1,
                                          w1t, P1, h1, t_s, ah[s], wgp, mode);
      k_fwd<<<dim3(256, 4), 256, 0, stream>>>(h1, P2, b2, P3, kpart);
    }
  }
  k_out<<<dim3(512), 256, 0, stream>>>(th, acb, kpart, b3, (float*)d_out, hs / 6.f);
}

// Round 13
// 389.885 us; speedup vs baseline: 1.3837x; 1.2639x over previous
//
#include <hip/hip_runtime.h>

#define NSTEPS 2
#define SN (8192 * 64)

typedef unsigned short u16;
typedef unsigned int   u32;
typedef unsigned long long u64;
typedef __bf16 bf16x8 __attribute__((ext_vector_type(8)));
typedef float  f32x4  __attribute__((ext_vector_type(4)));

typedef __attribute__((address_space(1))) void gvoid_t;
typedef __attribute__((address_space(3))) void lvoid_t;

__device__ __forceinline__ void async_copy16(const void* g, void* l) {
  __builtin_amdgcn_global_load_lds((gvoid_t*)g, (lvoid_t*)l, 16, 0, 0);
}
__device__ __forceinline__ u16 bfc(float x) {
  union { __bf16 b; u16 u; } v; v.b = (__bf16)x; return v.u;
}
__device__ __forceinline__ u64 pack4(float a, float b, float c, float d) {
  return (u64)bfc(a) | ((u64)bfc(b) << 16) | ((u64)bfc(c) << 32) | ((u64)bfc(d) << 48);
}
__device__ __forceinline__ float ftanh(float x) {
  float e = __expf(2.f * x);
  return 1.f - 2.f / (e + 1.f);
}

// ---------------- prep kernels ----------------

// base1[j] = b1[j] + sum_c ctx[c] * W1[(65+c)*1024 + j]
__global__ __launch_bounds__(256) void k_base1(
    const float* __restrict__ W1, const float* __restrict__ b1,
    const float* __restrict__ ctx, float* __restrict__ base1) {
  int j = blockIdx.x * 256 + threadIdx.x;
  float s = b1[j];
  for (int c = 0; c < 256; ++c)
    s += ctx[c] * W1[(size_t)(65 + c) * 1024 + j];
  base1[j] = s;
}

// Pack W[K][N] f32 -> fragment-linear bf16: fid = nt*KS + ks, lane holds
// W[ks*32+(lane>>4)*8+j][nt*16+(lane&15)], j=0..7.  frag = 1024B.
__global__ __launch_bounds__(256) void k_pack(
    const float* __restrict__ W, u16* __restrict__ P, int ksl, int N) {
  int gid = blockIdx.x * 256 + threadIdx.x;
  int lane = gid & 63, fid = gid >> 6;
  int ks = fid & ((1 << ksl) - 1);
  int nt = fid >> ksl;
  int n  = nt * 16 + (lane & 15);
  int k0 = ks * 32 + (lane >> 4) * 8;
  u64 lo = pack4(W[(size_t)k0 * N + n], W[(size_t)(k0 + 1) * N + n],
                 W[(size_t)(k0 + 2) * N + n], W[(size_t)(k0 + 3) * N + n]);
  u64 hi = pack4(W[(size_t)(k0 + 4) * N + n], W[(size_t)(k0 + 5) * N + n],
                 W[(size_t)(k0 + 6) * N + n], W[(size_t)(k0 + 7) * N + n]);
  u64* dst = (u64*)(P + (size_t)gid * 8);
  dst[0] = lo; dst[1] = hi;
}

// ---------------- k_l1: RK-update + layer1 (h1 computed ONCE) ----------------
__global__ __launch_bounds__(512, 4) void k_l1(
    const float* __restrict__ theta0, float* __restrict__ th,
    float* __restrict__ acb, const float* __restrict__ kpart,
    const float* __restrict__ b3, const float* __restrict__ base1,
    const float* __restrict__ w1t, const u16* __restrict__ P1,
    u16* __restrict__ h1, float t_s, float a_h, float wgp, int mode) {
  __shared__ u16 xs[32 * 64];          // 4 KB, 128B rows, slot ^= row&7
  __shared__ float bias[1024];         // 4 KB
  __shared__ u16 bounce[8][32 * 16];   // 8 KB, 1 KB per wave
  const int tid = threadIdx.x, wid = tid >> 6, lane = tid & 63;
  const int lrow = lane & 15, lk4 = lane >> 4;
  const int brow = blockIdx.x * 32;

  bias[tid]       = base1[tid]       + t_s * w1t[tid];
  bias[tid + 512] = base1[tid + 512] + t_s * w1t[tid + 512];

  {
    int row = tid >> 4, d = (tid & 15) * 4;
    int gi = (brow + row) * 64 + d;
    f32x4 x;
    if (mode == 0) {
      x = *(const f32x4*)(theta0 + gi);
    } else {
      f32x4 kv = *(const f32x4*)(kpart + gi);
      f32x4 k1 = *(const f32x4*)(kpart + SN + gi);
      f32x4 k2 = *(const f32x4*)(kpart + 2 * SN + gi);
      f32x4 k3 = *(const f32x4*)(kpart + 3 * SN + gi);
      f32x4 bv = *(const f32x4*)(b3 + d);
      f32x4 t  = *(f32x4*)(th + gi);
      f32x4 a  = *(f32x4*)(acb + gi);
#pragma unroll
      for (int j = 0; j < 4; ++j) kv[j] += k1[j] + k2[j] + k3[j] + bv[j];
      if (mode == 1) {
#pragma unroll
        for (int j = 0; j < 4; ++j) { a[j] += wgp * kv[j]; x[j] = t[j] + a_h * kv[j]; }
        *(f32x4*)(acb + gi) = a;
      } else {
#pragma unroll
        for (int j = 0; j < 4; ++j) t[j] += a[j] + wgp * kv[j];
        *(f32x4*)(th + gi) = t;
        f32x4 z = {0.f, 0.f, 0.f, 0.f};
        *(f32x4*)(acb + gi) = z;
        x = t;
      }
    }
    int slot = d >> 3, half = (d >> 2) & 1;
    *(u64*)((char*)xs + row * 128 + ((slot ^ (row & 7)) << 4) + half * 8)
        = pack4(x[0], x[1], x[2], x[3]);
  }
  __syncthreads();

  u16* bnc = &bounce[wid][0];
#pragma unroll 1
  for (int nt = 0; nt < 8; ++nt) {
    const int n0 = wid * 128 + nt * 16;
    f32x4 acc[2] = {{0.f,0.f,0.f,0.f},{0.f,0.f,0.f,0.f}};
#pragma unroll
    for (int ks = 0; ks < 2; ++ks) {
      bf16x8 pw = *(const bf16x8*)(P1 + ((size_t)((n0 >> 4) * 2 + ks) << 9) + lane * 8);
#pragma unroll
      for (int st = 0; st < 2; ++st) {
        int row = st * 16 + lrow;
        bf16x8 xa = *(const bf16x8*)((char*)xs + row * 128 +
                                     (((ks * 4 + lk4) ^ (row & 7)) << 4));
        acc[st] = __builtin_amdgcn_mfma_f32_16x16x32_bf16(pw, xa, acc[st], 0, 0, 0);
      }
    }
    float bb0 = bias[n0 + lk4 * 4], bb1 = bias[n0 + lk4 * 4 + 1];
    float bb2 = bias[n0 + lk4 * 4 + 2], bb3 = bias[n0 + lk4 * 4 + 3];
#pragma unroll
    for (int st = 0; st < 2; ++st) {
      u64 pk = pack4(ftanh(acc[st][0] + bb0), ftanh(acc[st][1] + bb1),
                     ftanh(acc[st][2] + bb2), ftanh(acc[st][3] + bb3));
      *(u64*)((char*)bnc + (st * 16 + lrow) * 32 + lk4 * 8) = pk;
    }
    asm volatile("s_waitcnt lgkmcnt(0)" ::: "memory");
    bf16x8 ld = *(const bf16x8*)((char*)bnc + lane * 16);
    *(bf16x8*)(h1 + (size_t)(brow + (lane >> 1)) * 1024 + n0 + (lane & 1) * 8) = ld;
  }
}

// ---------------- k_fwd: layer2 + tanh + layer3-partial ----------------
// Tile 32 samples x 256 h2 cols (grid 256 x 4), 256 thr = 4 waves, BK=64.
// A (h1): LDS dbuf, 2-deep counted-vmcnt prefetch.
// B (W2): register-streamed from fragment-linear P2, prefetched a FULL
// ITERATION ahead. STATIC registers: manual 2x unroll with NAMED BfE/BfO
// (rule #20 — round 12's Bf[t&1] dyn-index spilled to scratch: 104 MB
// writes). vmcnt FIFO: 9 ops/iter; A(t) retire = 9 (t=0) / 17 / 16 (t=15).
__global__ __launch_bounds__(256, 3) void k_fwd(
    const u16* __restrict__ h1, const u16* __restrict__ P2,
    const float* __restrict__ b2, const u16* __restrict__ P3,
    float* __restrict__ kpart) {
  __shared__ u16 Ab[2][32 * 64];     // 2 x 4 KB
  __shared__ u16 h2L[32 * 256];      // 16 KB
  __shared__ float b2l[256];         // 1 KB
  const int tid = threadIdx.x, wid = tid >> 6, lane = tid & 63;
  const int lrow = lane & 15, lk4 = lane >> 4;
  const int brow = blockIdx.x * 32, bcol = blockIdx.y * 256;
  const int wn = wid;                 // wave col-block (4 x 64 cols)

  b2l[tid] = b2[bcol + tid];

  auto stageA = [&](int buf, int k0) {
    int pr = tid >> 3, s8u = (tid & 7) ^ (pr & 7);
    async_copy16((const char*)h1 + ((size_t)(brow + pr) * 1024 + k0 + s8u * 8) * 2,
                 (char*)&Ab[buf][0] + tid * 16);
  };

  const u16* Pw = P2 + ((size_t)((bcol >> 4) + wn * 4) * 32 << 9) + lane * 8;
  bf16x8 BfE[2][4], BfO[2][4];
#define LOADB(B, ks)                                                        \
  {                                                                         \
    _Pragma("unroll")                                                       \
    for (int n = 0; n < 4; ++n) {                                           \
      B[0][n] = *(const bf16x8*)(Pw + (((size_t)(n * 32 + (ks))) << 9));    \
      B[1][n] = *(const bf16x8*)(Pw + (((size_t)(n * 32 + (ks) + 1)) << 9));\
    }                                                                       \
  }

  // prologue: A 2-deep; B both slices for iter 0
  stageA(0, 0);
  asm volatile("" ::: "memory");
  stageA(1, 64);
  asm volatile("" ::: "memory");
  LOADB(BfE, 0);

  f32x4 acc[4][2] = {};
  int cur = 0;

#define ITER(T, BC, BN)                                                     \
  {                                                                         \
    if ((T) == 0)       asm volatile("s_waitcnt vmcnt(9)"  ::: "memory");   \
    else if ((T) == 15) asm volatile("s_waitcnt vmcnt(16)" ::: "memory");   \
    else                asm volatile("s_waitcnt vmcnt(17)" ::: "memory");   \
    __builtin_amdgcn_s_barrier();                                           \
    bf16x8 af0[2], af1[2];                                                  \
    _Pragma("unroll")                                                       \
    for (int m = 0; m < 2; ++m) {                                           \
      int ar = m * 16 + lrow;                                               \
      const char* Arow = (const char*)&Ab[cur][0] + ar * 128;               \
      af0[m] = *(const bf16x8*)(Arow + ((lk4 ^ (ar & 7)) << 4));            \
      af1[m] = *(const bf16x8*)(Arow + (((4 + lk4) ^ (ar & 7)) << 4));      \
    }                                                                       \
    asm volatile("s_waitcnt lgkmcnt(0)" ::: "memory");                      \
    __builtin_amdgcn_s_barrier();                                           \
    asm volatile("" ::: "memory");                                          \
    if ((T) < 14) stageA(cur, ((T) + 2) * 64);                              \
    asm volatile("" ::: "memory");                                          \
    if ((T) < 15) LOADB(BN, 2 * (T) + 2);                                   \
    _Pragma("unroll")                                                       \
    for (int n = 0; n < 4; ++n)                                             \
      _Pragma("unroll")                                                     \
      for (int m = 0; m < 2; ++m)                                           \
        acc[n][m] = __builtin_amdgcn_mfma_f32_16x16x32_bf16(BC[0][n], af0[m],\
                                                            acc[n][m], 0, 0, 0);\
    _Pragma("unroll")                                                       \
    for (int n = 0; n < 4; ++n)                                             \
      _Pragma("unroll")                                                     \
      for (int m = 0; m < 2; ++m)                                           \
        acc[n][m] = __builtin_amdgcn_mfma_f32_16x16x32_bf16(BC[1][n], af1[m],\
                                                            acc[n][m], 0, 0, 0);\
    cur ^= 1;                                                               \
  }

#pragma unroll 1
  for (int tt = 0; tt < 8; ++tt) {
    ITER(2 * tt,     BfE, BfO);
    ITER(2 * tt + 1, BfO, BfE);
  }
#undef ITER
#undef LOADB

  // h2 tile: tanh -> h2L[32][256] (512B rows), swizzled 16B slots
#pragma unroll
  for (int n = 0; n < 4; ++n) {
    int cb = wn * 64 + n * 16 + lk4 * 4;     // 4 consecutive cols
    float c0 = b2l[cb], c1 = b2l[cb + 1], c2 = b2l[cb + 2], c3 = b2l[cb + 3];
    int o = cb >> 3, half = (cb >> 2) & 1;
#pragma unroll
    for (int m = 0; m < 2; ++m) {
      int smp = m * 16 + lrow;
      u64 pk = pack4(ftanh(acc[n][m][0] + c0), ftanh(acc[n][m][1] + c1),
                     ftanh(acc[n][m][2] + c2), ftanh(acc[n][m][3] + c3));
      int sl = (o & 24) | ((o & 7) ^ (smp & 7));
      *(u64*)((char*)h2L + smp * 512 + (sl << 4) + half * 8) = pk;
    }
  }
  __syncthreads();

  // L3 partial: D[kcol][sample]; wave = 32 kcols x 16 samples, K=256
  {
    const int st = wid >> 1, ktp = wid & 1;
    const int smp = st * 16 + lrow;
    const char* Ar = (const char*)h2L + smp * 512;
    const int sx = smp & 7;
    f32x4 a3[2] = {};
#pragma unroll
    for (int ks = 0; ks < 8; ++ks) {
      int slu = ks * 4 + lk4;
      bf16x8 hf = *(const bf16x8*)(Ar + (((slu & 24) | ((slu & 7) ^ sx)) << 4));
#pragma unroll
      for (int n = 0; n < 2; ++n) {
        int fid = (ktp * 2 + n) * 32 + blockIdx.y * 8 + ks;
        bf16x8 pw = *(const bf16x8*)(P3 + ((size_t)fid << 9) + lane * 8);
        a3[n] = __builtin_amdgcn_mfma_f32_16x16x32_bf16(pw, hf, a3[n], 0, 0, 0);
      }
    }
    float* kp = kpart + (size_t)blockIdx.y * SN;
#pragma unroll
    for (int n = 0; n < 2; ++n)
      *(f32x4*)(kp + (size_t)(brow + smp) * 64 + (ktp * 2 + n) * 16 + lk4 * 4) = a3[n];
  }
}

// ---------------- final output ----------------
__global__ __launch_bounds__(256) void k_out(
    const float* __restrict__ th, const float* __restrict__ acb,
    const float* __restrict__ kpart, const float* __restrict__ b3,
    float* __restrict__ out, float w) {
  int gi = (blockIdx.x * 256 + threadIdx.x) * 4;
  f32x4 kv = *(const f32x4*)(kpart + gi);
  f32x4 k1 = *(const f32x4*)(kpart + SN + gi);
  f32x4 k2 = *(const f32x4*)(kpart + 2 * SN + gi);
  f32x4 k3 = *(const f32x4*)(kpart + 3 * SN + gi);
  f32x4 bv = *(const f32x4*)(b3 + (gi & 63));
  f32x4 t  = *(const f32x4*)(th + gi);
  f32x4 a  = *(const f32x4*)(acb + gi);
#pragma unroll
  for (int j = 0; j < 4; ++j)
    t[j] += a[j] + w * (kv[j] + k1[j] + k2[j] + k3[j] + bv[j]);
  *(f32x4*)(out + gi) = t;
}

// ---------------- host ----------------

extern "C" void kernel_launch(void* const* d_in, const int* in_sizes, int n_in,
                              void* d_out, int out_size, void* d_ws, size_t ws_size,
                              hipStream_t stream) {
  const float* theta0 = (const float*)d_in[0];
  const float* ctx    = (const float*)d_in[1];
  const float* W1     = (const float*)d_in[2];
  const float* b1     = (const float*)d_in[3];
  const float* W2     = (const float*)d_in[4];
  const float* b2     = (const float*)d_in[5];
  const float* W3     = (const float*)d_in[6];
  const float* b3     = (const float*)d_in[7];
  const float* w1t    = W1 + (size_t)64 * 1024;   // time row of W1

  char* ws = (char*)d_ws;
  size_t o = 0;
  float* th    = (float*)(ws + o); o += (size_t)SN * 4;            // 2 MB
  float* acb   = (float*)(ws + o); o += (size_t)SN * 4;            // 2 MB
  float* base1 = (float*)(ws + o); o += 4096;
  u16* P2  = (u16*)(ws + o); o += (size_t)1024 * 1024 * 2;         // 2 MB
  u16* P1  = (u16*)(ws + o); o += (size_t)64 * 1024 * 2;           // 128 KB
  u16* P3  = (u16*)(ws + o); o += (size_t)1024 * 64 * 2;           // 128 KB
  float* kpart = (float*)(ws + o); o += (size_t)4 * SN * 4;        // 8 MB
  u16* h1  = (u16*)(ws + o); o += (size_t)8192 * 1024 * 2;         // 16 MB

  hipMemcpyAsync(th, theta0, (size_t)SN * 4, hipMemcpyDeviceToDevice, stream);
  hipMemsetAsync(acb, 0, (size_t)SN * 4, stream);

  k_base1<<<dim3(4), 256, 0, stream>>>(W1, b1, ctx, base1);
  k_pack<<<dim3(512), 256, 0, stream>>>(W2, P2, 5, 1024);  // 64 nt x 32 ks
  k_pack<<<dim3(32),  256, 0, stream>>>(W1, P1, 1, 1024);  // 64 nt x 2 ks
  k_pack<<<dim3(32),  256, 0, stream>>>(W3, P3, 5, 64);    // 4 nt x 32 ks

  const float hs = 1.f / NSTEPS;
  const float ah[4] = {0.f, 0.5f * hs, 0.5f * hs, hs};
  const float ct[4] = {0.f, 0.5f, 0.5f, 1.f};

  for (int step = 0; step < NSTEPS; ++step) {
    for (int s = 0; s < 4; ++s) {
      int mode = (step == 0 && s == 0) ? 0 : (s == 0 ? 2 : 1);
      float wgp = (s == 0 || s == 1) ? hs / 6.f : hs / 3.f;
      float t_s = ((float)step + ct[s]) * hs;
      k_l1<<<dim3(256), 512, 0, stream>>>(theta0, th, acb, kpart, b3, base1,
                                          w1t, P1, h1, t_s, ah[s], wgp, mode);
      k_fwd<<<dim3(256, 4), 256, 0, stream>>>(h1, P2, b2, P3, kpart);
    }
  }
  k_out<<<dim3(512), 256, 0, stream>>>(th, acb, kpart, b3, (float*)d_out, hs / 6.f);
}